// Round 1
// baseline (24998.642 us; speedup 1.0000x reference)
//
#include <hip/hip_runtime.h>

typedef _Float16 f16;
typedef _Float16 f16x8 __attribute__((ext_vector_type(8)));
typedef float f32x4 __attribute__((ext_vector_type(4)));
typedef float fl4 __attribute__((ext_vector_type(4)));

#define DEVFN static __device__ __forceinline__

#define NBLK 160
#define NTHR 256
#define GTOT (NBLK*NTHR)

// ---------------- workspace layout (bytes), all 256-aligned ----------------
#define OFF_WCAT 0ULL
#define OFF_WT1  (OFF_WCAT + 2048ULL*768*2)
#define OFF_A    (OFF_WT1  + 512ULL*1024*2)
#define OFF_GATES (OFF_A   + 256ULL*1280*2)
#define OFF_H    (OFF_GATES + 256ULL*2048*4)
#define OFF_C    (OFF_H    + 131072ULL*4)
#define OFF_HIST (OFF_C    + 131072ULL*4)
#define OFF_HSUM (OFF_HIST + 5ULL*131072*4)
#define OFF_BSUM (OFF_HSUM + 131072ULL*4)
#define OFF_U    (OFF_BSUM + 2048ULL*4)
#define OFF_V    (OFF_U    + 512ULL*256*4)
#define OFF_CU   (OFF_V    + 512ULL*256*4)
#define OFF_CV   (OFF_CU   + 512ULL*4)
#define OFF_ZETA (OFF_CV   + 512ULL*4)
#define OFF_RES  (OFF_ZETA + 512ULL*4)
#define OFF_TENS (OFF_RES  + 512ULL*256*4)
#define OFF_BAR  (OFF_TENS + 2ULL*256*4)

__constant__ float CGAM[15] = {14.134725f, 21.02204f, 25.010858f, 30.424876f, 32.935062f,
  37.586178f, 40.91872f, 43.327073f, 48.005151f, 49.773832f, 52.970321f,
  56.446248f, 59.347044f, 60.831779f, 65.112544f};

DEVFN float sigf(float v) { return 1.f / (1.f + __expf(-v)); }
DEVFN float tanh_(float v) {
  v = fminf(fmaxf(v, -15.f), 15.f);
  float e = __expf(2.f * v);
  return (e - 1.f) / (e + 1.f);
}

DEVFN void gl_lds16(const void* g, void* l) {
  __builtin_amdgcn_global_load_lds((__attribute__((address_space(1))) void*)g,
                                   (__attribute__((address_space(3))) void*)l, 16, 0, 0);
}

// monotonic-counter grid barrier (all NBLK blocks co-resident: 1 block/CU, 160<=256)
DEVFN void gbar(unsigned int* bar, unsigned int target) {
  __syncthreads();
  if (threadIdx.x == 0) {
    __threadfence();
    __hip_atomic_fetch_add(bar, 1u, __ATOMIC_RELEASE, __HIP_MEMORY_SCOPE_AGENT);
    int spins = 0;
    while (__hip_atomic_load(bar, __ATOMIC_ACQUIRE, __HIP_MEMORY_SCOPE_AGENT) < target) {
      __builtin_amdgcn_s_sleep(1);
      if (++spins > (1 << 22)) break;   // safety bailout, never hit in healthy runs
    }
    __threadfence();
  }
  __syncthreads();
}

// ---------------- init: weight conversion + state zeroing ----------------
__global__ void k_init(const float* __restrict__ x, const float* __restrict__ Wih,
                       const float* __restrict__ Whh, const float* __restrict__ bih,
                       const float* __restrict__ bhh, const float* __restrict__ Wt1f,
                       char* __restrict__ ws) {
  f16* Wcat = (f16*)(ws + OFF_WCAT);
  f16* Wt1h = (f16*)(ws + OFF_WT1);
  f16* A    = (f16*)(ws + OFF_A);
  float* hbuf = (float*)(ws + OFF_H);
  float* cbuf = (float*)(ws + OFF_C);
  float* hist = (float*)(ws + OFF_HIST);
  float* hsum = (float*)(ws + OFF_HSUM);
  float* bsum = (float*)(ws + OFF_BSUM);
  float* tens = (float*)(ws + OFF_TENS);
  int gtid = blockIdx.x * blockDim.x + threadIdx.x;
  int nth = gridDim.x * blockDim.x;
  for (int i = gtid; i < 2048 * 768; i += nth) {
    int n = i / 768, k = i - n * 768;
    float w = (k < 256) ? Wih[n * 256 + k] : Whh[n * 512 + (k - 256)];
    Wcat[i] = (f16)w;
  }
  for (int i = gtid; i < 512 * 1024; i += nth) Wt1h[i] = (f16)Wt1f[i];
  for (int i = gtid; i < 2048; i += nth) bsum[i] = bih[i] + bhh[i];
  for (int i = gtid; i < 256 * 1280; i += nth) {
    int b = i / 1280, k = i - b * 1280;
    A[i] = (k < 256) ? (f16)x[(size_t)b * 131072 + k] : (f16)0.f;  // x[b][0][k]; h,hmean = 0
  }
  for (int i = gtid; i < 131072; i += nth) { hbuf[i] = 0.f; cbuf[i] = 0.f; hsum[i] = 0.f; }
  for (int i = gtid; i < 5 * 131072; i += nth) hist[i] = 0.f;
  for (int i = gtid; i < 512; i += nth) tens[i] = 0.f;
  if (gtid == 0) *(unsigned int*)(ws + OFF_BAR) = 0u;
}

// ---------------- per-t tables: u,v (resonance factorization), cu,cv, zeta ----------------
__global__ void k_tables(const float* __restrict__ Wproj, const float* __restrict__ bproj,
                         char* __restrict__ ws) {
  float* u    = (float*)(ws + OFF_U);
  float* v    = (float*)(ws + OFF_V);
  float* cu   = (float*)(ws + OFF_CU);
  float* cv   = (float*)(ws + OFF_CV);
  float* zeta = (float*)(ws + OFF_ZETA);
  int t = blockIdx.x;
  int k = threadIdx.x;
  float tf = (float)t;
  float cg[15], sg[15], ph[15];
  #pragma unroll
  for (int m = 0; m < 15; ++m) {
    float ang = CGAM[m] * tf;
    cg[m] = cosf(ang);
    sg[m] = sinf(ang);
    ph[m] = (float)exp(-0.1 * (double)CGAM[m]);
  }
  float uu = 0.f, vv = 0.f;
  #pragma unroll
  for (int m = 0; m < 15; ++m) {
    uu += Wproj[m * 256 + k] * cg[m] * ph[m];
    vv += Wproj[(15 + m) * 256 + k] * sg[m] * ph[m];
  }
  u[t * 256 + k] = uu;
  v[t * 256 + k] = vv;
  if (k == 0) {
    float a = 0.f, b2 = 0.f, z = 0.f;
    #pragma unroll
    for (int m = 0; m < 15; ++m) {
      a  += bproj[m] * cg[m] * ph[m];
      b2 += bproj[15 + m] * sg[m] * ph[m];
      z  += ph[m] * cg[m];
    }
    cu[t] = a; cv[t] = b2; zeta[t] = z / 15.f;
  }
}

// ---------------- resonance[b,t] for all (b,t): one wave per pair ----------------
__global__ void k_res(const float* __restrict__ x, char* __restrict__ ws) {
  const float* u  = (const float*)(ws + OFF_U);
  const float* v  = (const float*)(ws + OFF_V);
  const float* cu = (const float*)(ws + OFF_CU);
  const float* cv = (const float*)(ws + OFF_CV);
  float* resb     = (float*)(ws + OFF_RES);
  int wid = blockIdx.x * 4 + (threadIdx.x >> 6);
  int l = threadIdx.x & 63;
  int b = wid >> 9, t = wid & 511;
  const fl4 xx = *(const fl4*)(x + ((size_t)(b * 512 + t)) * 256 + l * 4);
  const fl4 uu = *(const fl4*)(u + t * 256 + l * 4);
  const fl4 vv = *(const fl4*)(v + t * 256 + l * 4);
  float cc = xx[0]*uu[0] + xx[1]*uu[1] + xx[2]*uu[2] + xx[3]*uu[3];
  float ss = xx[0]*vv[0] + xx[1]*vv[1] + xx[2]*vv[2] + xx[3]*vv[3];
  #pragma unroll
  for (int m = 1; m < 64; m <<= 1) { cc += __shfl_xor(cc, m); ss += __shfl_xor(ss, m); }
  if (l == 0) {
    cc += cu[t]; ss += cv[t];
    float r = sqrtf(cc * cc + ss * ss + 1e-8f) - 0.5f;
    resb[t * 256 + b] = sigf(r);
  }
}

// ---------------- persistent recurrent kernel ----------------
__global__ void __launch_bounds__(256, 1)
k_lstm(const float* __restrict__ x, const float* __restrict__ bt1,
       const float* __restrict__ wt2, const float* __restrict__ bt2,
       const float* __restrict__ wg, const float* __restrict__ bg,
       float* __restrict__ out, char* __restrict__ ws) {
  const f16* Wcat = (const f16*)(ws + OFF_WCAT);
  const f16* Wt1h = (const f16*)(ws + OFF_WT1);
  f16* A       = (f16*)(ws + OFF_A);
  float* gates = (float*)(ws + OFF_GATES);
  float* hbuf  = (float*)(ws + OFF_H);
  float* cbuf  = (float*)(ws + OFF_C);
  float* hist  = (float*)(ws + OFF_HIST);
  float* hsum  = (float*)(ws + OFF_HSUM);
  const float* bsum = (const float*)(ws + OFF_BSUM);
  const float* zeta = (const float*)(ws + OFF_ZETA);
  const float* resb = (const float*)(ws + OFF_RES);
  float* tens  = (float*)(ws + OFF_TENS);
  unsigned int* bar = (unsigned int*)(ws + OFF_BAR);

  __shared__ __align__(16) f16 sA[64 * 64];
  __shared__ __align__(16) f16 sB[64 * 64];

  const int tid = threadIdx.x;
  const int w = tid >> 6, l = tid & 63;
  const int job = blockIdx.x;
  const bool isT1 = (job >= 128);
  int m0, n0, kbeg, kend, koff, wstr;
  const f16* W;
  if (!isT1) { m0 = (job >> 5) * 64; n0 = (job & 31) * 64; kbeg = 0;   kend = 768;  koff = 0;   wstr = 768;  W = Wcat; }
  else { int j = job - 128; m0 = (j >> 3) * 64; n0 = (j & 7) * 64;     kbeg = 256; kend = 1280; koff = 256; wstr = 1024; W = Wt1h; }
  const int m_off = (w >> 1) * 32, n_off = (w & 1) * 32;
  const int srow0 = w * 16 + (l >> 3);   // staging row (+8 per i)
  const int sc8   = l & 7;               // staging 16B-block within row
  const float wg0 = wg[0], wg1 = wg[1], bt2v = bt2[0], bgv = bg[0];
  const int gtid = blockIdx.x * 256 + tid;
  unsigned int phase = 0;

  for (int t = 0; t < 512; ++t) {
    // ================= phase 1: MFMA tile job =================
    f32x4 acc00 = {0.f,0.f,0.f,0.f}, acc01 = {0.f,0.f,0.f,0.f};
    f32x4 acc10 = {0.f,0.f,0.f,0.f}, acc11 = {0.f,0.f,0.f,0.f};
    for (int kc = kbeg; kc < kend; kc += 64) {
      #pragma unroll
      for (int i = 0; i < 2; ++i) {
        int row = srow0 + i * 8;
        int csrc = (sc8 ^ (row & 7)) * 8;   // inverse-swizzled source column (elements)
        gl_lds16(A + (size_t)(m0 + row) * 1280 + kc + csrc, (char*)sA + w * 2048 + i * 1024);
        gl_lds16(W + (size_t)(n0 + row) * wstr + (kc - koff) + csrc, (char*)sB + w * 2048 + i * 1024);
      }
      __syncthreads();
      #pragma unroll
      for (int ks = 0; ks < 2; ++ks) {
        f16x8 a0, a1, b0, b1;
        { int r = m_off + (l & 15);      a0 = *(const f16x8*)((const char*)sA + r * 128 + (((ks * 4 + (l >> 4)) ^ (r & 7)) << 4)); }
        { int r = m_off + 16 + (l & 15); a1 = *(const f16x8*)((const char*)sA + r * 128 + (((ks * 4 + (l >> 4)) ^ (r & 7)) << 4)); }
        { int r = n_off + (l & 15);      b0 = *(const f16x8*)((const char*)sB + r * 128 + (((ks * 4 + (l >> 4)) ^ (r & 7)) << 4)); }
        { int r = n_off + 16 + (l & 15); b1 = *(const f16x8*)((const char*)sB + r * 128 + (((ks * 4 + (l >> 4)) ^ (r & 7)) << 4)); }
        acc00 = __builtin_amdgcn_mfma_f32_16x16x32_f16(a0, b0, acc00, 0, 0, 0);
        acc01 = __builtin_amdgcn_mfma_f32_16x16x32_f16(a0, b1, acc01, 0, 0, 0);
        acc10 = __builtin_amdgcn_mfma_f32_16x16x32_f16(a1, b0, acc10, 0, 0, 0);
        acc11 = __builtin_amdgcn_mfma_f32_16x16x32_f16(a1, b1, acc11, 0, 0, 0);
      }
      __syncthreads();
    }
    if (!isT1) {
      int gr = m0 + m_off + ((l >> 4) << 2);
      int gc = n0 + n_off + (l & 15);
      #pragma unroll
      for (int r = 0; r < 4; ++r) {
        gates[(gr + r) * 2048 + gc]           = acc00[r];
        gates[(gr + r) * 2048 + gc + 16]      = acc01[r];
        gates[(gr + 16 + r) * 2048 + gc]      = acc10[r];
        gates[(gr + 16 + r) * 2048 + gc + 16] = acc11[r];
      }
    } else {
      int n_a = n0 + n_off + (l & 15);
      int n_b = n_a + 16;
      float wa = wt2[n_a], ba = bt1[n_a];
      float wb = wt2[n_b], bb = bt1[n_b];
      float* tensb = tens + (t & 1) * 256;
      #pragma unroll
      for (int mi = 0; mi < 2; ++mi) {
        f32x4 va = mi ? acc10 : acc00;
        f32x4 vb = mi ? acc11 : acc01;
        float sr[4];
        #pragma unroll
        for (int r = 0; r < 4; ++r)
          sr[r] = fmaxf(va[r] + ba, 0.f) * wa + fmaxf(vb[r] + bb, 0.f) * wb;
        #pragma unroll
        for (int m = 1; m < 16; m <<= 1) {
          #pragma unroll
          for (int r = 0; r < 4; ++r) sr[r] += __shfl_xor(sr[r], m);
        }
        if ((l & 15) == 0) {
          int brow = m0 + m_off + mi * 16 + ((l >> 4) << 2);
          #pragma unroll
          for (int r = 0; r < 4; ++r) atomicAdd(&tensb[brow + r], sr[r]);
        }
      }
    }
    ++phase; gbar(bar, phase * NBLK);
    // ================= phase 2: elementwise recurrence =================
    const float zt = zeta[t];
    for (int idx = gtid; idx < 131072; idx += GTOT) {
      int b = idx >> 9;
      int j = idx & 511;
      const float* grow = gates + b * 2048;
      float gi = grow[j]        + bsum[j];
      float gf = grow[512 + j]  + bsum[512 + j];
      float gg = grow[1024 + j] + bsum[1024 + j];
      float go = grow[1536 + j] + bsum[1536 + j];
      float c_old = cbuf[idx];
      float cn = sigf(gf) * c_old + sigf(gi) * tanh_(gg);
      float hn = sigf(go) * tanh_(cn);
      float tn = (t < 2) ? 0.f : sigf(tens[(t & 1) * 256 + b] + bt2v);
      float rs = resb[t * 256 + b];
      float gate = sigf(wg0 * rs + wg1 * tn + bgv);
      float h_old = hbuf[idx];
      float hout = hn + gate * (zt * h_old);
      cbuf[idx] = cn;
      hbuf[idx] = hout;
      out[((size_t)b * 512 + (size_t)t) * 512 + j] = hout;
      A[b * 1280 + 256 + j] = (f16)hout;
      int slot = (t + 1) % 5;
      float* hp = hist + (size_t)slot * 131072 + idx;
      float old5 = *hp;
      float nsum = hsum[idx] - old5 + hout;
      *hp = hout;
      hsum[idx] = nsum;
      A[b * 1280 + 768 + j] = (f16)(nsum * 0.2f);
      if (t == 511) {
        out[67108864 + idx] = hout;          // h_n
        out[67108864 + 131072 + idx] = cn;   // c_n
      }
    }
    if (t < 511) {
      for (int idx = gtid; idx < 65536; idx += GTOT) {
        int b = idx >> 8, k = idx & 255;
        A[b * 1280 + k] = (f16)x[((size_t)(b * 512 + t + 1)) * 256 + k];
      }
    }
    if (gtid < 256) tens[((t + 1) & 1) * 256 + gtid] = 0.f;
    ++phase; gbar(bar, phase * NBLK);
  }
}

extern "C" void kernel_launch(void* const* d_in, const int* in_sizes, int n_in,
                              void* d_out, int out_size, void* d_ws, size_t ws_size,
                              hipStream_t stream) {
  (void)in_sizes; (void)n_in; (void)out_size; (void)ws_size;
  const float* x     = (const float*)d_in[0];
  const float* Wih   = (const float*)d_in[1];
  const float* Whh   = (const float*)d_in[2];
  const float* bih   = (const float*)d_in[3];
  const float* bhh   = (const float*)d_in[4];
  const float* Wproj = (const float*)d_in[5];
  const float* bproj = (const float*)d_in[6];
  const float* Wt1   = (const float*)d_in[7];
  const float* bt1   = (const float*)d_in[8];
  const float* Wt2   = (const float*)d_in[9];
  const float* bt2   = (const float*)d_in[10];
  const float* Wg    = (const float*)d_in[11];
  const float* bg    = (const float*)d_in[12];
  float* out = (float*)d_out;
  char* ws = (char*)d_ws;
  k_init<<<dim3(1024), dim3(256), 0, stream>>>(x, Wih, Whh, bih, bhh, Wt1, ws);
  k_tables<<<dim3(512), dim3(256), 0, stream>>>(Wproj, bproj, ws);
  k_res<<<dim3(32768), dim3(256), 0, stream>>>(x, ws);
  k_lstm<<<dim3(NBLK), dim3(256), 0, stream>>>(x, bt1, Wt2, bt2, Wg, bg, out, ws);
}